// Round 11
// baseline (165.119 us; speedup 1.0000x reference)
//
#include <hip/hip_runtime.h>
#include <cstddef>

#define NB   8
#define NPTS 4096
#define KNN  16
#define FCAP 64    // per-query collected-candidate capacity

typedef _Float16 h2 __attribute__((ext_vector_type(2)));
typedef _Float16 h8 __attribute__((ext_vector_type(8)));
typedef float    f4 __attribute__((ext_vector_type(4)));

static __device__ __forceinline__ h2 pk2(float a, float b) {
    return __builtin_bit_cast(h2, __builtin_amdgcn_cvt_pkrtz(a, b));
}
static __device__ __forceinline__ unsigned bch(h2 v) {
    return __builtin_bit_cast(unsigned, v);
}

#if __has_builtin(__builtin_amdgcn_fmed3f)
static __device__ __forceinline__ float MED3(float a, float b, float c) {
    return __builtin_amdgcn_fmed3f(a, b, c);
}
#else
static __device__ __forceinline__ float MED3(float a, float b, float c) {
    return fmaxf(fminf(a, b), fminf(fmaxf(a, b), c));
}
#endif

// Exact f32 distance (sq-form). Same fmaf nesting as prep's sq -> self-dist
// is exactly 0. Used ONLY for the exact candidate distances.
static __device__ __forceinline__ float dist2(float4 Q, float4 p) {
    float dot = fmaf(Q.z, p.z, fmaf(Q.y, p.y, Q.x * p.x));
    return fmaf(-2.0f, dot, Q.w + p.w);
}

// ---------------------------------------------------------------------------
// Kernel P: pack pts4[b][n] = (x, y, z, x*x+y*y+z*z) from xyz[B][3][N]
// ---------------------------------------------------------------------------
__global__ __launch_bounds__(256) void prep_kernel(const float* __restrict__ xyz,
                                                   float4* __restrict__ pts4) {
    int i = blockIdx.x * 256 + threadIdx.x;
    int b = i >> 12;
    int n = i & (NPTS - 1);
    const float* base = xyz + (size_t)b * 3 * NPTS;
    float x = base[n];
    float y = base[NPTS + n];
    float z = base[2 * NPTS + n];
    float sq = fmaf(z, z, fmaf(y, y, x * x));   // same nesting as dist2's dot
    pts4[i] = make_float4(x, y, z, sq);
}

// ---------------------------------------------------------------------------
// Kernel A: exact 16-NN with SPLIT-PRECISION MFMA pruning keys.
//  Key k(c) = s(c) - 2q.p(c) evaluated with f16 hi/lo splits (≈22-bit inputs):
//   A row (cand): k0..7 = [x_hi,x_lo,y_hi,y_lo,z_hi,z_lo,s_hi,s_lo] (lanes 0-15)
//                 k8..10 = [x_hi,y_hi,z_hi]                        (lanes 16-31)
//   B col (query): k0..7 = [ux_hi,ux_hi,uy_hi,uy_hi,uz_hi,uz_hi,1,1]
//                  k8..10 = [ux_lo,uy_lo,uz_lo]        (u = -2q, hi/lo split)
//  => g = (p_hi+p_lo).u_hi + p_hi.u_lo + s_hi + s_lo; |g - k_exact| <= E with
//  E = (smax + 8 pmax^2) * 2e-6 + 1e-4  (rigorous: all residuals O(2^-22 scale);
//  was 0.033 in round 10 -> qcnt ballooned -> serial fallback fired ~27% of
//  blocks at ~34us each. Now qcnt ~17-20, fallback probability ~0.)
//  Phase 1: per-lane sorted-4 (min+3 med3) -> 64 partials/query -> tau_hat.
//  Phase 2: same deterministic MFMA, collect g <= tau_hat + 2E (LDS atomic).
//  Sweep: parallel exact f32 distances; final: lexicographic (d,idx) top-16
//  == jax.lax.top_k tie-break. FCAP overflow -> exact brute-force (safety).
// ---------------------------------------------------------------------------
__global__ __launch_bounds__(1024, 8) void knn_kernel(const float4* __restrict__ pts4,
                                                      int* __restrict__ idxout) {
    __shared__ uint4 PmA[NPTS];                       // 64 KB split-f16 rows
    __shared__ char  sbuf[32768];                     // 32 KB phase-shared
    __shared__ float tauv[64];
    __shared__ int   qcnt[64];
    __shared__ unsigned pmaxu, smaxu;

    float*    partials = (float*)sbuf;                // [64 slots][64 q] 16 KB
    float*    mbuf     = (float*)(sbuf + 16384);      // [4*16][64 q]    16 KB
    unsigned* fidx     = (unsigned*)sbuf;             // [FCAP][64 q]    16 KB
    float*    fdist    = (float*)(sbuf + 16384);      // [FCAP][64 q]    16 KB

    int tid = threadIdx.x;
    int b   = blockIdx.y;
    const float4* pb = pts4 + (size_t)b * NPTS;

    if (tid == 0) { pmaxu = 0u; smaxu = 0u; }
    __syncthreads();

    // ---- stage split-f16 rows; reduce exact pmax/smax of the batch ----
    {
        float lm = 0.0f, ls = 0.0f;
        for (int j = tid; j < NPTS; j += 1024) {
            float4 p = pb[j];
            lm = fmaxf(lm, fmaxf(fabsf(p.x), fmaxf(fabsf(p.y), fabsf(p.z))));
            ls = fmaxf(ls, p.w);
            _Float16 xh = (_Float16)p.x, yh = (_Float16)p.y;
            _Float16 zh = (_Float16)p.z, sh = (_Float16)p.w;
            _Float16 xl = (_Float16)(p.x - (float)xh);
            _Float16 yl = (_Float16)(p.y - (float)yh);
            _Float16 zl = (_Float16)(p.z - (float)zh);
            _Float16 sl = (_Float16)(p.w - (float)sh);
            h2 ax = {xh, xl}, ay = {yh, yl}, az = {zh, zl}, as = {sh, sl};
            PmA[j] = make_uint4(bch(ax), bch(ay), bch(az), bch(as));
        }
        atomicMax(&pmaxu, __builtin_bit_cast(unsigned, lm));   // f32>=0: uint order
        atomicMax(&smaxu, __builtin_bit_cast(unsigned, ls));
    }

    int wave = tid >> 6, lane = tid & 63;
    int qg = wave >> 2;           // query group 0..3 (16 q each)
    int cq = wave & 3;            // candidate quarter 0..3 (1024 cands)
    int qcol = lane & 15;         // A-row / B-col / D-col
    int rg   = lane >> 4;         // k-slot group
    int q  = qg * 16 + qcol;
    int nq = (blockIdx.x << 6) + q;
    int cbase = cq * 1024;

    float4 qf = pb[nq];
    float uxf = -2.0f * qf.x, uyf = -2.0f * qf.y, uzf = -2.0f * qf.z;  // exact
    _Float16 uxh = (_Float16)uxf, uyh = (_Float16)uyf, uzh = (_Float16)uzf;
    _Float16 uxl = (_Float16)(uxf - (float)uxh);
    _Float16 uyl = (_Float16)(uyf - (float)uyh);
    _Float16 uzl = (_Float16)(uzf - (float)uzh);
    uint4 bu = {0u, 0u, 0u, 0u};
    if (rg == 0) {
        h2 b01 = {uxh, uxh}, b23 = {uyh, uyh};
        h2 b45 = {uzh, uzh}, b67 = {(_Float16)1.0f, (_Float16)1.0f};
        bu.x = bch(b01); bu.y = bch(b23); bu.z = bch(b45); bu.w = bch(b67);
    } else if (rg == 1) {
        h2 b89 = {uxl, uyl}, bAB = {uzl, (_Float16)0.0f};
        bu.x = bch(b89); bu.y = bch(bAB);
    }
    h8 bq = __builtin_bit_cast(h8, bu);
    __syncthreads();

    auto afrag = [&](int t) -> h8 {
        uint4 au = {0u, 0u, 0u, 0u};
        if (rg < 2) {
            uint4 pd = PmA[cbase + t * 16 + qcol];
            if (rg == 0) {
                au = pd;
            } else {
                au.x = (pd.x & 0xFFFFu) | ((pd.y & 0xFFFFu) << 16);  // x_hi,y_hi
                au.y = (pd.z & 0xFFFFu);                             // z_hi
            }
        }
        return __builtin_bit_cast(h8, au);
    };

    // ---- phase 1: 64 MFMA tiles, per-lane sorted-4 via min+med3 ----
    {
        float c0 = __builtin_inff(), c1 = c0, c2 = c0, c3 = c0;
#pragma unroll 2
        for (int t = 0; t < 64; ++t) {
            f4 d = __builtin_amdgcn_mfma_f32_16x16x32_f16(afrag(t), bq, (f4)0.0f, 0, 0, 0);
#pragma unroll
            for (int r = 0; r < 4; ++r) {
                float x = d[r];
                float p0 = c0, p1 = c1, p2 = c2;
                c0 = fminf(p0, x);
                c1 = MED3(x, p0, c1);
                c2 = MED3(x, p1, c2);
                c3 = MED3(x, p2, c3);
            }
        }
        int sb = (cq * 4 + rg) * 4;
        partials[(sb + 0) * 64 + q] = c0;
        partials[(sb + 1) * 64 + q] = c1;
        partials[(sb + 2) * 64 + q] = c2;
        partials[(sb + 3) * 64 + q] = c3;
    }
    __syncthreads();

    // ---- merge level 1: 4 mergers/query x 16 slots -> sorted-16 ----
    if (tid < 256) {
        int qq = tid & 63, k = tid >> 6;
        float mb[16];
#pragma unroll
        for (int j = 0; j < 16; ++j) mb[j] = __builtin_inff();
        for (int s = 0; s < 16; ++s) {
            float v = partials[(k * 16 + s) * 64 + qq];
            float prev = mb[0];
            mb[0] = fminf(mb[0], v);
#pragma unroll
            for (int i = 1; i < 16; ++i) {
                float cur = mb[i];
                mb[i] = MED3(v, prev, cur);
                prev = cur;
            }
        }
#pragma unroll
        for (int j = 0; j < 16; ++j) mbuf[(k * 16 + j) * 64 + qq] = mb[j];
    }
    __syncthreads();

    // ---- merge level 2: 16th of 4 sorted lists; tight rigorous threshold ----
    if (tid < 64) {
        float mb[16];
#pragma unroll
        for (int j = 0; j < 16; ++j) mb[j] = __builtin_inff();
        for (int k = 0; k < 4; ++k) {
            for (int j = 0; j < 16; ++j) {
                float v = mbuf[(k * 16 + j) * 64 + tid];
                if (v >= mb[15]) break;             // ascending list
                float prev = mb[0];
                mb[0] = fminf(mb[0], v);
#pragma unroll
                for (int i = 1; i < 16; ++i) {
                    float cur = mb[i];
                    mb[i] = MED3(v, prev, cur);
                    prev = cur;
                }
            }
        }
        float pmax = __builtin_bit_cast(float, pmaxu);
        float smax = __builtin_bit_cast(float, smaxu);
        // all split-key residuals are O(2^-22 * scale); 2e-6 covers with 2x slack
        float E = (smax + 8.0f * pmax * pmax) * 2e-6f + 1e-4f;
        tauv[tid] = mb[15] + 2.0f * E;
        qcnt[tid] = 0;
    }
    __syncthreads();   // partials/mbuf dead; reuse as fidx/fdist

    // ---- phase 2: same MFMA (deterministic), push indices with g <= tau_c ----
    {
        float tc = tauv[q];
#pragma unroll 2
        for (int t = 0; t < 64; ++t) {
            f4 d = __builtin_amdgcn_mfma_f32_16x16x32_f16(afrag(t), bq, (f4)0.0f, 0, 0, 0);
#pragma unroll
            for (int r = 0; r < 4; ++r) {
                if (d[r] <= tc) {
                    int pos = atomicAdd(&qcnt[q], 1);
                    if (pos < FCAP) fidx[pos * 64 + q] = (unsigned)(cbase + t * 16 + rg * 4 + r);
                }
            }
        }
    }
    __syncthreads();

    // ---- sweep: exact f32 distances, fully parallel gathers ----
    for (int e = tid; e < FCAP * 64; e += 1024) {
        int j = e >> 6, qq = e & 63;
        int nc = qcnt[qq]; nc = nc > FCAP ? FCAP : nc;
        if (j < nc) {
            float4 Qf = pb[(blockIdx.x << 6) + qq];
            fdist[e] = dist2(Qf, pb[fidx[e]]);
        }
    }
    __syncthreads();

    // ---- final: lexicographic (d asc, idx asc) top-16; overflow fallback ----
    if (tid < 64) {
        int nqf = (blockIdx.x << 6) + tid;
        float4 Qf = pb[nqf];
        float bd[16]; int bi[16];
#pragma unroll
        for (int j = 0; j < 16; ++j) { bd[j] = __builtin_inff(); bi[j] = 0; }
        int cnt = qcnt[tid];
        if (cnt <= FCAP) {
            for (int j = 0; j < cnt; ++j) {
                float x  = fdist[j * 64 + tid];
                int   xi = (int)fidx[j * 64 + tid];
                if (x < bd[15] || (x == bd[15] && xi < bi[15])) {
#pragma unroll
                    for (int t = 0; t < 16; ++t) {
                        bool c = (x < bd[t]) || (x == bd[t] && xi < bi[t]);
                        float nd = c ? x  : bd[t];
                        int   ni = c ? xi : bi[t];
                        float od = c ? bd[t] : x;
                        int   oi = c ? bi[t] : xi;
                        bd[t] = nd; bi[t] = ni; x = od; xi = oi;
                    }
                }
            }
        } else {
            // safety fallback: exact brute-force scan (probability ~0 now)
            for (int m = 0; m < NPTS; ++m) {
                float x = dist2(Qf, pb[m]);
                int  xi = m;
                if (x < bd[15] || (x == bd[15] && xi < bi[15])) {
#pragma unroll
                    for (int t = 0; t < 16; ++t) {
                        bool c = (x < bd[t]) || (x == bd[t] && xi < bi[t]);
                        float nd = c ? x  : bd[t];
                        int   ni = c ? xi : bi[t];
                        float od = c ? bd[t] : x;
                        int   oi = c ? bi[t] : xi;
                        bd[t] = nd; bi[t] = ni; x = od; xi = oi;
                    }
                }
            }
        }
        int* op = idxout + ((size_t)b * NPTS + nqf) * KNN;
#pragma unroll
        for (int j = 0; j < 16; ++j) op[j] = bi[j];
    }
}

// ---------------------------------------------------------------------------
// Kernel B: fully-register MFMA MLP (unchanged from rounds 4-10).
// ---------------------------------------------------------------------------
__global__ __launch_bounds__(256, 2) void mlp_kernel(
    const float4* __restrict__ pts4, const int* __restrict__ idxin,
    const float* __restrict__ W0, const float* __restrict__ b0,
    const float* __restrict__ W1, const float* __restrict__ b1,
    const float* __restrict__ W2, const float* __restrict__ b2,
    float* __restrict__ out) {

    int tid  = threadIdx.x;
    int wave = tid >> 6, lane = tid & 63;
    int g = lane >> 4, i = lane & 15;

    h2 w0x[8], w0y[8], w0z[8], w0b[8];
#pragma unroll
    for (int s = 0; s < 2; ++s)
#pragma unroll
        for (int v = 0; v < 4; ++v) {
            int c0 = 32 * s + 8 * g + 2 * v;
            w0x[s * 4 + v] = pk2(W0[c0 * 3 + 0], W0[c0 * 3 + 3]);
            w0y[s * 4 + v] = pk2(W0[c0 * 3 + 1], W0[c0 * 3 + 4]);
            w0z[s * 4 + v] = pk2(W0[c0 * 3 + 2], W0[c0 * 3 + 5]);
            w0b[s * 4 + v] = pk2(b0[c0], b0[c0 + 1]);
        }
    h2 b1p[8];
#pragma unroll
    for (int s = 0; s < 2; ++s)
#pragma unroll
        for (int v = 0; v < 4; ++v) {
            int c0 = 32 * s + 16 * (v >> 1) + 4 * g + 2 * (v & 1);
            b1p[s * 4 + v] = pk2(b1[c0], b1[c0 + 1]);
        }
    h8 wf1[4][2];
#pragma unroll
    for (int t = 0; t < 4; ++t)
#pragma unroll
        for (int s = 0; s < 2; ++s) {
            const float* p = W1 + (16 * t + i) * 64 + 32 * s + 8 * g;
            h8 f;
#pragma unroll
            for (int j = 0; j < 8; ++j) f[j] = (_Float16)p[j];
            wf1[t][s] = f;
        }
    h8 wf2[8][2];
#pragma unroll
    for (int t = 0; t < 8; ++t)
#pragma unroll
        for (int s = 0; s < 2; ++s) {
            const float* p = W2 + (16 * t + i) * 64;
            h8 f;
#pragma unroll
            for (int j = 0; j < 8; ++j) {
                int vc = 32 * s + 16 * (j >> 2) + 4 * g + (j & 3);
                f[j] = (_Float16)p[vc];
            }
            wf2[t][s] = f;
        }

    int gw = blockIdx.x * 4 + wave;
    int b  = gw >> 8;
    int n0 = (gw & 255) * 16;

    const float4* pb = pts4 + (size_t)b * NPTS;
    float4 q = pb[n0 + i];
    const int* ip = idxin + ((size_t)b * NPTS + n0 + i) * KNN;

    float mx[8][4];
#pragma unroll
    for (int t = 0; t < 8; ++t)
#pragma unroll
        for (int r = 0; r < 4; ++r) mx[t][r] = -3.4e38f;

    for (int it = 0; it < KNN; ++it) {
        int mi = ip[it];
        float4 p = pb[mi];
        float rx = p.x - q.x, ry = p.y - q.y, rz = p.z - q.z;
        h2 rxx = pk2(rx, rx), ryy = pk2(ry, ry), rzz = pk2(rz, rz);

        h8 h0f[2];
#pragma unroll
        for (int s = 0; s < 2; ++s)
#pragma unroll
            for (int v = 0; v < 4; ++v) {
                h2 hh = __builtin_elementwise_fma(w0z[s * 4 + v], rzz,
                         __builtin_elementwise_fma(w0y[s * 4 + v], ryy,
                          __builtin_elementwise_fma(w0x[s * 4 + v], rxx, w0b[s * 4 + v])));
                hh = __builtin_elementwise_max(hh, (h2)(_Float16)0.0f);
                h0f[s][2 * v]     = hh.x;
                h0f[s][2 * v + 1] = hh.y;
            }

        f4 d1[4];
#pragma unroll
        for (int t = 0; t < 4; ++t) {
            d1[t] = (f4)0.0f;
#pragma unroll
            for (int s = 0; s < 2; ++s)
                d1[t] = __builtin_amdgcn_mfma_f32_16x16x32_f16(wf1[t][s], h0f[s], d1[t], 0, 0, 0);
        }

        h8 h1f[2];
#pragma unroll
        for (int s = 0; s < 2; ++s)
#pragma unroll
            for (int v = 0; v < 4; ++v) {
                int t = 2 * s + (v >> 1), r0 = 2 * (v & 1);
                h2 w = pk2(d1[t][r0], d1[t][r0 + 1]);
                w = w + b1p[s * 4 + v];
                w = __builtin_elementwise_max(w, (h2)(_Float16)0.0f);
                h1f[s][2 * v]     = w.x;
                h1f[s][2 * v + 1] = w.y;
            }

#pragma unroll
        for (int t = 0; t < 8; ++t) {
            f4 d2 = (f4)0.0f;
#pragma unroll
            for (int s = 0; s < 2; ++s)
                d2 = __builtin_amdgcn_mfma_f32_16x16x32_f16(wf2[t][s], h1f[s], d2, 0, 0, 0);
#pragma unroll
            for (int r = 0; r < 4; ++r) mx[t][r] = fmaxf(mx[t][r], d2[r]);
        }
    }

    size_t ob = (size_t)b * 128 * NPTS + n0 + i;
#pragma unroll
    for (int t = 0; t < 8; ++t)
#pragma unroll
        for (int r = 0; r < 4; ++r) {
            int chn = 16 * t + 4 * g + r;
            float v = fmaxf(mx[t][r] + b2[chn], 0.0f);
            out[ob + (size_t)chn * NPTS] = v;
        }
}

// ---------------------------------------------------------------------------
extern "C" void kernel_launch(void* const* d_in, const int* in_sizes, int n_in,
                              void* d_out, int out_size, void* d_ws, size_t ws_size,
                              hipStream_t stream) {
    (void)in_sizes; (void)n_in; (void)out_size; (void)ws_size;
    const float* xyz = (const float*)d_in[0];
    const float* W0  = (const float*)d_in[1];
    const float* b0  = (const float*)d_in[2];
    const float* W1  = (const float*)d_in[3];
    const float* b1  = (const float*)d_in[4];
    const float* W2  = (const float*)d_in[5];
    const float* b2  = (const float*)d_in[6];
    float* out = (float*)d_out;

    char* ws = (char*)d_ws;
    float4* pts4 = (float4*)ws;                                     // 512 KB
    int*    idxb = (int*)(ws + (size_t)NB * NPTS * sizeof(float4)); // 2 MB

    prep_kernel<<<dim3(NB * NPTS / 256), dim3(256), 0, stream>>>(xyz, pts4);
    knn_kernel<<<dim3(NPTS / 64, NB), dim3(1024), 0, stream>>>(pts4, idxb);
    mlp_kernel<<<dim3(512), dim3(256), 0, stream>>>(
        pts4, idxb, W0, b0, W1, b1, W2, b2, out);
}

// Round 12
// 128.419 us; speedup vs baseline: 1.2858x; 1.2858x over previous
//
#include <hip/hip_runtime.h>
#include <cstddef>

#define NB   8
#define NPTS 4096
#define KNN  16
#define FCAP 64    // per-query collected-candidate capacity

typedef _Float16 h2 __attribute__((ext_vector_type(2)));
typedef _Float16 h8 __attribute__((ext_vector_type(8)));
typedef float    f4 __attribute__((ext_vector_type(4)));

static __device__ __forceinline__ h2 pk2(float a, float b) {
    return __builtin_bit_cast(h2, __builtin_amdgcn_cvt_pkrtz(a, b));
}
static __device__ __forceinline__ unsigned bch(h2 v) {
    return __builtin_bit_cast(unsigned, v);
}

#if __has_builtin(__builtin_amdgcn_fmed3f)
static __device__ __forceinline__ float MED3(float a, float b, float c) {
    return __builtin_amdgcn_fmed3f(a, b, c);
}
#else
static __device__ __forceinline__ float MED3(float a, float b, float c) {
    return fmaxf(fminf(a, b), fminf(fmaxf(a, b), c));
}
#endif

// Exact f32 distance (sq-form). Same fmaf nesting as prep's sq -> self-dist
// is exactly 0. Used ONLY for the exact candidate distances.
static __device__ __forceinline__ float dist2(float4 Q, float4 p) {
    float dot = fmaf(Q.z, p.z, fmaf(Q.y, p.y, Q.x * p.x));
    return fmaf(-2.0f, dot, Q.w + p.w);
}

// ---------------------------------------------------------------------------
// Kernel P: pack pts4[b][n] = (x, y, z, x*x+y*y+z*z) from xyz[B][3][N]
// ---------------------------------------------------------------------------
__global__ __launch_bounds__(256) void prep_kernel(const float* __restrict__ xyz,
                                                   float4* __restrict__ pts4) {
    int i = blockIdx.x * 256 + threadIdx.x;
    int b = i >> 12;
    int n = i & (NPTS - 1);
    const float* base = xyz + (size_t)b * 3 * NPTS;
    float x = base[n];
    float y = base[NPTS + n];
    float z = base[2 * NPTS + n];
    float sq = fmaf(z, z, fmaf(y, y, x * x));   // same nesting as dist2's dot
    pts4[i] = make_float4(x, y, z, sq);
}

// ---------------------------------------------------------------------------
// Kernel A: exact 16-NN, MFMA pruning keys (round-10 structure) with a
// per-query TIGHT error bound (round-11's goal, without its LDS/occupancy
// cost). A row (cand) uses k0..3 AND k4..7 = (xh,yh,zh,sh) -- the same uint2
// staged bytes, duplicated into the high half of the fragment (no repack,
// no extra LDS). B col (query): k0..3 = (uxh,uyh,uzh,1), k4..7 =
// (uxl,uyl,uzl,0) with u = -2q split hi/lo. Key g = p_h.(u_h+u_l) + s_h.
// Residual terms: s_lo and x_lo*u only.
//  E0  = smax*2^-11 + 2*sum|q|*pmax*2^-11 + 1e-3          (all candidates)
//  R   = |q| + sqrt(tau_hat + 2 E0 + |q|^2)               (reach of relevant c)
//  E_q = min((R^2 + 2*sum|q|*R)*2^-11 + 6e-4, E0)         (relevant c only)
// Chain: {g<=tau} => k<=tau+E0 => |p|<=R => E(c)<=E_q => tau* <= tau+E_q
//        => collect g <= tau + 2 E_q covers the exact top-16.   qcnt ~17-23,
// FCAP-overflow probability ~1e-10 => the serial fallback (the round-10
// bottleneck) never executes. Exact f32 lexicographic final select unchanged.
// ---------------------------------------------------------------------------
__global__ __launch_bounds__(1024, 8) void knn_kernel(const float4* __restrict__ pts4,
                                                      int* __restrict__ idxout) {
    __shared__ uint2 Pm[NPTS];                        // 32 KB (xh,yh | zh,sh)
    __shared__ char  sbuf[32768];                     // 32 KB phase-shared
    __shared__ float tauv[64];
    __shared__ int   qcnt[64];
    __shared__ unsigned pmaxu, smaxu;

    float*    partials = (float*)sbuf;                // [64 slots][64 q] 16 KB
    float*    mbuf     = (float*)(sbuf + 16384);      // [4*16][64 q]    16 KB
    unsigned* fidx     = (unsigned*)sbuf;             // [FCAP][64 q]    16 KB
    float*    fdist    = (float*)(sbuf + 16384);      // [FCAP][64 q]    16 KB

    int tid = threadIdx.x;
    int b   = blockIdx.y;
    const float4* pb = pts4 + (size_t)b * NPTS;

    if (tid == 0) { pmaxu = 0u; smaxu = 0u; }
    __syncthreads();

    // ---- stage (xh,yh|zh,sh); reduce exact pmax/smax of the batch ----
    {
        float lm = 0.0f, ls = 0.0f;
        for (int j = tid; j < NPTS; j += 1024) {
            float4 p = pb[j];
            lm = fmaxf(lm, fmaxf(fabsf(p.x), fmaxf(fabsf(p.y), fabsf(p.z))));
            ls = fmaxf(ls, p.w);
            h2 lo = { (_Float16)p.x, (_Float16)p.y };
            h2 hi = { (_Float16)p.z, (_Float16)p.w };
            Pm[j].x = bch(lo);
            Pm[j].y = bch(hi);
        }
        atomicMax(&pmaxu, __builtin_bit_cast(unsigned, lm));   // f32>=0: uint order
        atomicMax(&smaxu, __builtin_bit_cast(unsigned, ls));
    }

    int wave = tid >> 6, lane = tid & 63;
    int qg = wave >> 2;           // query group 0..3 (16 q each)
    int cq = wave & 3;            // candidate quarter 0..3 (1024 cands)
    int qcol = lane & 15;         // A-row / B-col / D-col
    int rg   = lane >> 4;         // D row group / k-slot group
    int q  = qg * 16 + qcol;
    int nq = (blockIdx.x << 6) + q;
    int cbase = cq * 1024;

    float4 qf = pb[nq];
    float uxf = -2.0f * qf.x, uyf = -2.0f * qf.y, uzf = -2.0f * qf.z;  // exact
    _Float16 uxh = (_Float16)uxf, uyh = (_Float16)uyf, uzh = (_Float16)uzf;
    _Float16 uxl = (_Float16)(uxf - (float)uxh);
    _Float16 uyl = (_Float16)(uyf - (float)uyh);
    _Float16 uzl = (_Float16)(uzf - (float)uzh);
    uint4 bu = {0u, 0u, 0u, 0u};
    if (rg == 0) {
        h2 b01 = {uxh, uyh}, b23 = {uzh, (_Float16)1.0f};
        h2 b45 = {uxl, uyl}, b67 = {uzl, (_Float16)0.0f};
        bu.x = bch(b01); bu.y = bch(b23); bu.z = bch(b45); bu.w = bch(b67);
    }
    h8 bq = __builtin_bit_cast(h8, bu);
    __syncthreads();

    // ---- phase 1: 64 MFMA tiles, per-lane sorted-4 via min+med3 ----
    {
        float c0 = __builtin_inff(), c1 = c0, c2 = c0, c3 = c0;
#pragma unroll 2
        for (int t = 0; t < 64; ++t) {
            uint4 au = {0u, 0u, 0u, 0u};
            if (rg == 0) {
                uint2 pd = Pm[cbase + t * 16 + qcol];
                au.x = pd.x; au.y = pd.y; au.z = pd.x; au.w = pd.y;  // k0-3 & k4-7
            }
            f4 d = __builtin_amdgcn_mfma_f32_16x16x32_f16(
                __builtin_bit_cast(h8, au), bq, (f4)0.0f, 0, 0, 0);
#pragma unroll
            for (int r = 0; r < 4; ++r) {
                float x = d[r];
                float p0 = c0, p1 = c1, p2 = c2;
                c0 = fminf(p0, x);
                c1 = MED3(x, p0, c1);
                c2 = MED3(x, p1, c2);
                c3 = MED3(x, p2, c3);
            }
        }
        int sb = (cq * 4 + rg) * 4;
        partials[(sb + 0) * 64 + q] = c0;
        partials[(sb + 1) * 64 + q] = c1;
        partials[(sb + 2) * 64 + q] = c2;
        partials[(sb + 3) * 64 + q] = c3;
    }
    __syncthreads();

    // ---- merge level 1: 4 mergers/query x 16 slots -> sorted-16 ----
    if (tid < 256) {
        int qq = tid & 63, k = tid >> 6;
        float mb[16];
#pragma unroll
        for (int j = 0; j < 16; ++j) mb[j] = __builtin_inff();
        for (int s = 0; s < 16; ++s) {
            float v = partials[(k * 16 + s) * 64 + qq];
            float prev = mb[0];
            mb[0] = fminf(mb[0], v);
#pragma unroll
            for (int i = 1; i < 16; ++i) {
                float cur = mb[i];
                mb[i] = MED3(v, prev, cur);
                prev = cur;
            }
        }
#pragma unroll
        for (int j = 0; j < 16; ++j) mbuf[(k * 16 + j) * 64 + qq] = mb[j];
    }
    __syncthreads();

    // ---- merge level 2: 16th of 4 sorted lists; per-query tight bound ----
    if (tid < 64) {
        float mb[16];
#pragma unroll
        for (int j = 0; j < 16; ++j) mb[j] = __builtin_inff();
        for (int k = 0; k < 4; ++k) {
            for (int j = 0; j < 16; ++j) {
                float v = mbuf[(k * 16 + j) * 64 + tid];
                if (v >= mb[15]) break;             // ascending list
                float prev = mb[0];
                mb[0] = fminf(mb[0], v);
#pragma unroll
                for (int i = 1; i < 16; ++i) {
                    float cur = mb[i];
                    mb[i] = MED3(v, prev, cur);
                    prev = cur;
                }
            }
        }
        float4 q2 = pb[(blockIdx.x << 6) + tid];
        float sumq = fabsf(q2.x) + fabsf(q2.y) + fabsf(q2.z);
        float qn   = sqrtf(q2.w);                   // |q| (q2.w = |q|^2 >= 0)
        float pmax = __builtin_bit_cast(float, pmaxu);
        float smax = __builtin_bit_cast(float, smaxu);
        const float r11c = 4.8828125e-4f;           // 2^-11
        float tau = mb[15];
        float E0  = smax * r11c + 2.0f * sumq * pmax * r11c + 1.0e-3f;
        float rad2 = fmaxf(tau + 2.0f * E0 + q2.w, 0.0f);
        float R   = qn + sqrtf(rad2);
        float Eq  = (R * R + 2.0f * sumq * R) * r11c + 6.0e-4f;
        Eq = fminf(Eq, E0);
        tauv[tid] = tau + 2.0f * Eq;
        qcnt[tid] = 0;
    }
    __syncthreads();   // partials/mbuf dead; reuse as fidx/fdist

    // ---- phase 2: same MFMA (deterministic), push indices with g <= tau_c ----
    {
        float tc = tauv[q];
#pragma unroll 2
        for (int t = 0; t < 64; ++t) {
            uint4 au = {0u, 0u, 0u, 0u};
            if (rg == 0) {
                uint2 pd = Pm[cbase + t * 16 + qcol];
                au.x = pd.x; au.y = pd.y; au.z = pd.x; au.w = pd.y;
            }
            f4 d = __builtin_amdgcn_mfma_f32_16x16x32_f16(
                __builtin_bit_cast(h8, au), bq, (f4)0.0f, 0, 0, 0);
#pragma unroll
            for (int r = 0; r < 4; ++r) {
                if (d[r] <= tc) {
                    int pos = atomicAdd(&qcnt[q], 1);
                    if (pos < FCAP) fidx[pos * 64 + q] = (unsigned)(cbase + t * 16 + rg * 4 + r);
                }
            }
        }
    }
    __syncthreads();

    // ---- sweep: exact f32 distances, fully parallel gathers ----
    for (int e = tid; e < FCAP * 64; e += 1024) {
        int j = e >> 6, qq = e & 63;
        int nc = qcnt[qq]; nc = nc > FCAP ? FCAP : nc;
        if (j < nc) {
            float4 Qf = pb[(blockIdx.x << 6) + qq];
            fdist[e] = dist2(Qf, pb[fidx[e]]);
        }
    }
    __syncthreads();

    // ---- final: lexicographic (d asc, idx asc) top-16; overflow fallback ----
    if (tid < 64) {
        int nqf = (blockIdx.x << 6) + tid;
        float4 Qf = pb[nqf];
        float bd[16]; int bi[16];
#pragma unroll
        for (int j = 0; j < 16; ++j) { bd[j] = __builtin_inff(); bi[j] = 0; }
        int cnt = qcnt[tid];
        if (cnt <= FCAP) {
            for (int j = 0; j < cnt; ++j) {
                float x  = fdist[j * 64 + tid];
                int   xi = (int)fidx[j * 64 + tid];
                if (x < bd[15] || (x == bd[15] && xi < bi[15])) {
#pragma unroll
                    for (int t = 0; t < 16; ++t) {
                        bool c = (x < bd[t]) || (x == bd[t] && xi < bi[t]);
                        float nd = c ? x  : bd[t];
                        int   ni = c ? xi : bi[t];
                        float od = c ? bd[t] : x;
                        int   oi = c ? bi[t] : xi;
                        bd[t] = nd; bi[t] = ni; x = od; xi = oi;
                    }
                }
            }
        } else {
            // safety fallback: exact brute-force scan (P ~ 1e-10, never expected)
            for (int m = 0; m < NPTS; ++m) {
                float x = dist2(Qf, pb[m]);
                int  xi = m;
                if (x < bd[15] || (x == bd[15] && xi < bi[15])) {
#pragma unroll
                    for (int t = 0; t < 16; ++t) {
                        bool c = (x < bd[t]) || (x == bd[t] && xi < bi[t]);
                        float nd = c ? x  : bd[t];
                        int   ni = c ? xi : bi[t];
                        float od = c ? bd[t] : x;
                        int   oi = c ? bi[t] : xi;
                        bd[t] = nd; bi[t] = ni; x = od; xi = oi;
                    }
                }
            }
        }
        int* op = idxout + ((size_t)b * NPTS + nqf) * KNN;
#pragma unroll
        for (int j = 0; j < 16; ++j) op[j] = bi[j];
    }
}

// ---------------------------------------------------------------------------
// Kernel B: fully-register MFMA MLP (unchanged from rounds 4-11).
// ---------------------------------------------------------------------------
__global__ __launch_bounds__(256, 2) void mlp_kernel(
    const float4* __restrict__ pts4, const int* __restrict__ idxin,
    const float* __restrict__ W0, const float* __restrict__ b0,
    const float* __restrict__ W1, const float* __restrict__ b1,
    const float* __restrict__ W2, const float* __restrict__ b2,
    float* __restrict__ out) {

    int tid  = threadIdx.x;
    int wave = tid >> 6, lane = tid & 63;
    int g = lane >> 4, i = lane & 15;

    h2 w0x[8], w0y[8], w0z[8], w0b[8];
#pragma unroll
    for (int s = 0; s < 2; ++s)
#pragma unroll
        for (int v = 0; v < 4; ++v) {
            int c0 = 32 * s + 8 * g + 2 * v;
            w0x[s * 4 + v] = pk2(W0[c0 * 3 + 0], W0[c0 * 3 + 3]);
            w0y[s * 4 + v] = pk2(W0[c0 * 3 + 1], W0[c0 * 3 + 4]);
            w0z[s * 4 + v] = pk2(W0[c0 * 3 + 2], W0[c0 * 3 + 5]);
            w0b[s * 4 + v] = pk2(b0[c0], b0[c0 + 1]);
        }
    h2 b1p[8];
#pragma unroll
    for (int s = 0; s < 2; ++s)
#pragma unroll
        for (int v = 0; v < 4; ++v) {
            int c0 = 32 * s + 16 * (v >> 1) + 4 * g + 2 * (v & 1);
            b1p[s * 4 + v] = pk2(b1[c0], b1[c0 + 1]);
        }
    h8 wf1[4][2];
#pragma unroll
    for (int t = 0; t < 4; ++t)
#pragma unroll
        for (int s = 0; s < 2; ++s) {
            const float* p = W1 + (16 * t + i) * 64 + 32 * s + 8 * g;
            h8 f;
#pragma unroll
            for (int j = 0; j < 8; ++j) f[j] = (_Float16)p[j];
            wf1[t][s] = f;
        }
    h8 wf2[8][2];
#pragma unroll
    for (int t = 0; t < 8; ++t)
#pragma unroll
        for (int s = 0; s < 2; ++s) {
            const float* p = W2 + (16 * t + i) * 64;
            h8 f;
#pragma unroll
            for (int j = 0; j < 8; ++j) {
                int vc = 32 * s + 16 * (j >> 2) + 4 * g + (j & 3);
                f[j] = (_Float16)p[vc];
            }
            wf2[t][s] = f;
        }

    int gw = blockIdx.x * 4 + wave;
    int b  = gw >> 8;
    int n0 = (gw & 255) * 16;

    const float4* pb = pts4 + (size_t)b * NPTS;
    float4 q = pb[n0 + i];
    const int* ip = idxin + ((size_t)b * NPTS + n0 + i) * KNN;

    float mx[8][4];
#pragma unroll
    for (int t = 0; t < 8; ++t)
#pragma unroll
        for (int r = 0; r < 4; ++r) mx[t][r] = -3.4e38f;

    for (int it = 0; it < KNN; ++it) {
        int mi = ip[it];
        float4 p = pb[mi];
        float rx = p.x - q.x, ry = p.y - q.y, rz = p.z - q.z;
        h2 rxx = pk2(rx, rx), ryy = pk2(ry, ry), rzz = pk2(rz, rz);

        h8 h0f[2];
#pragma unroll
        for (int s = 0; s < 2; ++s)
#pragma unroll
            for (int v = 0; v < 4; ++v) {
                h2 hh = __builtin_elementwise_fma(w0z[s * 4 + v], rzz,
                         __builtin_elementwise_fma(w0y[s * 4 + v], ryy,
                          __builtin_elementwise_fma(w0x[s * 4 + v], rxx, w0b[s * 4 + v])));
                hh = __builtin_elementwise_max(hh, (h2)(_Float16)0.0f);
                h0f[s][2 * v]     = hh.x;
                h0f[s][2 * v + 1] = hh.y;
            }

        f4 d1[4];
#pragma unroll
        for (int t = 0; t < 4; ++t) {
            d1[t] = (f4)0.0f;
#pragma unroll
            for (int s = 0; s < 2; ++s)
                d1[t] = __builtin_amdgcn_mfma_f32_16x16x32_f16(wf1[t][s], h0f[s], d1[t], 0, 0, 0);
        }

        h8 h1f[2];
#pragma unroll
        for (int s = 0; s < 2; ++s)
#pragma unroll
            for (int v = 0; v < 4; ++v) {
                int t = 2 * s + (v >> 1), r0 = 2 * (v & 1);
                h2 w = pk2(d1[t][r0], d1[t][r0 + 1]);
                w = w + b1p[s * 4 + v];
                w = __builtin_elementwise_max(w, (h2)(_Float16)0.0f);
                h1f[s][2 * v]     = w.x;
                h1f[s][2 * v + 1] = w.y;
            }

#pragma unroll
        for (int t = 0; t < 8; ++t) {
            f4 d2 = (f4)0.0f;
#pragma unroll
            for (int s = 0; s < 2; ++s)
                d2 = __builtin_amdgcn_mfma_f32_16x16x32_f16(wf2[t][s], h1f[s], d2, 0, 0, 0);
#pragma unroll
            for (int r = 0; r < 4; ++r) mx[t][r] = fmaxf(mx[t][r], d2[r]);
        }
    }

    size_t ob = (size_t)b * 128 * NPTS + n0 + i;
#pragma unroll
    for (int t = 0; t < 8; ++t)
#pragma unroll
        for (int r = 0; r < 4; ++r) {
            int chn = 16 * t + 4 * g + r;
            float v = fmaxf(mx[t][r] + b2[chn], 0.0f);
            out[ob + (size_t)chn * NPTS] = v;
        }
}

// ---------------------------------------------------------------------------
extern "C" void kernel_launch(void* const* d_in, const int* in_sizes, int n_in,
                              void* d_out, int out_size, void* d_ws, size_t ws_size,
                              hipStream_t stream) {
    (void)in_sizes; (void)n_in; (void)out_size; (void)ws_size;
    const float* xyz = (const float*)d_in[0];
    const float* W0  = (const float*)d_in[1];
    const float* b0  = (const float*)d_in[2];
    const float* W1  = (const float*)d_in[3];
    const float* b1  = (const float*)d_in[4];
    const float* W2  = (const float*)d_in[5];
    const float* b2  = (const float*)d_in[6];
    float* out = (float*)d_out;

    char* ws = (char*)d_ws;
    float4* pts4 = (float4*)ws;                                     // 512 KB
    int*    idxb = (int*)(ws + (size_t)NB * NPTS * sizeof(float4)); // 2 MB

    prep_kernel<<<dim3(NB * NPTS / 256), dim3(256), 0, stream>>>(xyz, pts4);
    knn_kernel<<<dim3(NPTS / 64, NB), dim3(1024), 0, stream>>>(pts4, idxb);
    mlp_kernel<<<dim3(512), dim3(256), 0, stream>>>(
        pts4, idxb, W0, b0, W1, b1, W2, b2, out);
}

// Round 13
// 118.256 us; speedup vs baseline: 1.3963x; 1.0859x over previous
//
#include <hip/hip_runtime.h>
#include <cstddef>

#define NB   8
#define NPTS 4096
#define KNN  16
#define FCAP 64    // per-query collected-candidate capacity

typedef _Float16 h2 __attribute__((ext_vector_type(2)));
typedef _Float16 h8 __attribute__((ext_vector_type(8)));
typedef float    f4 __attribute__((ext_vector_type(4)));

static __device__ __forceinline__ h2 pk2(float a, float b) {
    return __builtin_bit_cast(h2, __builtin_amdgcn_cvt_pkrtz(a, b));
}
static __device__ __forceinline__ unsigned bch(h2 v) {
    return __builtin_bit_cast(unsigned, v);
}

#if __has_builtin(__builtin_amdgcn_fmed3f)
static __device__ __forceinline__ float MED3(float a, float b, float c) {
    return __builtin_amdgcn_fmed3f(a, b, c);
}
#else
static __device__ __forceinline__ float MED3(float a, float b, float c) {
    return fmaxf(fminf(a, b), fminf(fmaxf(a, b), c));
}
#endif

// Exact f32 distance (sq-form). Same fmaf nesting as prep's sq -> self-dist
// is exactly 0. Used ONLY for the exact candidate distances.
static __device__ __forceinline__ float dist2(float4 Q, float4 p) {
    float dot = fmaf(Q.z, p.z, fmaf(Q.y, p.y, Q.x * p.x));
    return fmaf(-2.0f, dot, Q.w + p.w);
}

// ---------------------------------------------------------------------------
// Kernel P: pack pts4[b][n] = (x, y, z, x*x+y*y+z*z) from xyz[B][3][N]
// ---------------------------------------------------------------------------
__global__ __launch_bounds__(256) void prep_kernel(const float* __restrict__ xyz,
                                                   float4* __restrict__ pts4) {
    int i = blockIdx.x * 256 + threadIdx.x;
    int b = i >> 12;
    int n = i & (NPTS - 1);
    const float* base = xyz + (size_t)b * 3 * NPTS;
    float x = base[n];
    float y = base[NPTS + n];
    float z = base[2 * NPTS + n];
    float sq = fmaf(z, z, fmaf(y, y, x * x));   // same nesting as dist2's dot
    pts4[i] = make_float4(x, y, z, sq);
}

// ---------------------------------------------------------------------------
// Kernel A: exact 16-NN, MFMA pruning keys (round-12 structure) with
// GROUP-MIN pre-reduction in the selection chains:
//  phase 1 inserts min(d0..d3) (3 v_min + 4-deep sorted chain = 7 VALU/MFMA,
//  was 16). Collected slots are still true candidate keys and a subset of all
//  keys, so tau_hat = 16th of 64 slots remains an upper bound of true tau
//  (slightly looser: top-4 of group-of-4 minima; qcnt ~18->23, FCAP absorbs).
//  phase 2 guards the per-register compare/push with the same rmin (3+1 ops).
// Everything else identical to round 12 (per-query tight E, parallel exact
// sweep, lexicographic final select == jax.lax.top_k tie-break).
// ---------------------------------------------------------------------------
__global__ __launch_bounds__(1024, 8) void knn_kernel(const float4* __restrict__ pts4,
                                                      int* __restrict__ idxout) {
    __shared__ uint2 Pm[NPTS];                        // 32 KB (xh,yh | zh,sh)
    __shared__ char  sbuf[32768];                     // 32 KB phase-shared
    __shared__ float tauv[64];
    __shared__ int   qcnt[64];
    __shared__ unsigned pmaxu, smaxu;

    float*    partials = (float*)sbuf;                // [64 slots][64 q] 16 KB
    float*    mbuf     = (float*)(sbuf + 16384);      // [4*16][64 q]    16 KB
    unsigned* fidx     = (unsigned*)sbuf;             // [FCAP][64 q]    16 KB
    float*    fdist    = (float*)(sbuf + 16384);      // [FCAP][64 q]    16 KB

    int tid = threadIdx.x;
    int b   = blockIdx.y;
    const float4* pb = pts4 + (size_t)b * NPTS;

    if (tid == 0) { pmaxu = 0u; smaxu = 0u; }
    __syncthreads();

    // ---- stage (xh,yh|zh,sh); reduce exact pmax/smax of the batch ----
    {
        float lm = 0.0f, ls = 0.0f;
        for (int j = tid; j < NPTS; j += 1024) {
            float4 p = pb[j];
            lm = fmaxf(lm, fmaxf(fabsf(p.x), fmaxf(fabsf(p.y), fabsf(p.z))));
            ls = fmaxf(ls, p.w);
            h2 lo = { (_Float16)p.x, (_Float16)p.y };
            h2 hi = { (_Float16)p.z, (_Float16)p.w };
            Pm[j].x = bch(lo);
            Pm[j].y = bch(hi);
        }
        atomicMax(&pmaxu, __builtin_bit_cast(unsigned, lm));   // f32>=0: uint order
        atomicMax(&smaxu, __builtin_bit_cast(unsigned, ls));
    }

    int wave = tid >> 6, lane = tid & 63;
    int qg = wave >> 2;           // query group 0..3 (16 q each)
    int cq = wave & 3;            // candidate quarter 0..3 (1024 cands)
    int qcol = lane & 15;         // A-row / B-col / D-col
    int rg   = lane >> 4;         // D row group / k-slot group
    int q  = qg * 16 + qcol;
    int nq = (blockIdx.x << 6) + q;
    int cbase = cq * 1024;

    float4 qf = pb[nq];
    float uxf = -2.0f * qf.x, uyf = -2.0f * qf.y, uzf = -2.0f * qf.z;  // exact
    _Float16 uxh = (_Float16)uxf, uyh = (_Float16)uyf, uzh = (_Float16)uzf;
    _Float16 uxl = (_Float16)(uxf - (float)uxh);
    _Float16 uyl = (_Float16)(uyf - (float)uyh);
    _Float16 uzl = (_Float16)(uzf - (float)uzh);
    uint4 bu = {0u, 0u, 0u, 0u};
    if (rg == 0) {
        h2 b01 = {uxh, uyh}, b23 = {uzh, (_Float16)1.0f};
        h2 b45 = {uxl, uyl}, b67 = {uzl, (_Float16)0.0f};
        bu.x = bch(b01); bu.y = bch(b23); bu.z = bch(b45); bu.w = bch(b67);
    }
    h8 bq = __builtin_bit_cast(h8, bu);
    __syncthreads();

    // ---- phase 1: 64 MFMA tiles, group-min + sorted-4 (7 VALU/tile) ----
    {
        float c0 = __builtin_inff(), c1 = c0, c2 = c0, c3 = c0;
#pragma unroll 2
        for (int t = 0; t < 64; ++t) {
            uint4 au = {0u, 0u, 0u, 0u};
            if (rg == 0) {
                uint2 pd = Pm[cbase + t * 16 + qcol];
                au.x = pd.x; au.y = pd.y; au.z = pd.x; au.w = pd.y;  // k0-3 & k4-7
            }
            f4 d = __builtin_amdgcn_mfma_f32_16x16x32_f16(
                __builtin_bit_cast(h8, au), bq, (f4)0.0f, 0, 0, 0);
            float rmin = fminf(fminf(d[0], d[1]), fminf(d[2], d[3]));
            float p0 = c0, p1 = c1, p2 = c2;
            c0 = fminf(p0, rmin);
            c1 = MED3(rmin, p0, c1);
            c2 = MED3(rmin, p1, c2);
            c3 = MED3(rmin, p2, c3);
        }
        int sb = (cq * 4 + rg) * 4;
        partials[(sb + 0) * 64 + q] = c0;
        partials[(sb + 1) * 64 + q] = c1;
        partials[(sb + 2) * 64 + q] = c2;
        partials[(sb + 3) * 64 + q] = c3;
    }
    __syncthreads();

    // ---- merge level 1: 4 mergers/query x 16 slots -> sorted-16 ----
    if (tid < 256) {
        int qq = tid & 63, k = tid >> 6;
        float mb[16];
#pragma unroll
        for (int j = 0; j < 16; ++j) mb[j] = __builtin_inff();
        for (int s = 0; s < 16; ++s) {
            float v = partials[(k * 16 + s) * 64 + qq];
            float prev = mb[0];
            mb[0] = fminf(mb[0], v);
#pragma unroll
            for (int i = 1; i < 16; ++i) {
                float cur = mb[i];
                mb[i] = MED3(v, prev, cur);
                prev = cur;
            }
        }
#pragma unroll
        for (int j = 0; j < 16; ++j) mbuf[(k * 16 + j) * 64 + qq] = mb[j];
    }
    __syncthreads();

    // ---- merge level 2: 16th of 4 sorted lists; per-query tight bound ----
    if (tid < 64) {
        float mb[16];
#pragma unroll
        for (int j = 0; j < 16; ++j) mb[j] = __builtin_inff();
        for (int k = 0; k < 4; ++k) {
            for (int j = 0; j < 16; ++j) {
                float v = mbuf[(k * 16 + j) * 64 + tid];
                if (v >= mb[15]) break;             // ascending list
                float prev = mb[0];
                mb[0] = fminf(mb[0], v);
#pragma unroll
                for (int i = 1; i < 16; ++i) {
                    float cur = mb[i];
                    mb[i] = MED3(v, prev, cur);
                    prev = cur;
                }
            }
        }
        float4 q2 = pb[(blockIdx.x << 6) + tid];
        float sumq = fabsf(q2.x) + fabsf(q2.y) + fabsf(q2.z);
        float qn   = sqrtf(q2.w);                   // |q| (q2.w = |q|^2 >= 0)
        float pmax = __builtin_bit_cast(float, pmaxu);
        float smax = __builtin_bit_cast(float, smaxu);
        const float r11c = 4.8828125e-4f;           // 2^-11
        float tau = mb[15];
        float E0  = smax * r11c + 2.0f * sumq * pmax * r11c + 1.0e-3f;
        float rad2 = fmaxf(tau + 2.0f * E0 + q2.w, 0.0f);
        float R   = qn + sqrtf(rad2);
        float Eq  = (R * R + 2.0f * sumq * R) * r11c + 6.0e-4f;
        Eq = fminf(Eq, E0);
        tauv[tid] = tau + 2.0f * Eq;
        qcnt[tid] = 0;
    }
    __syncthreads();   // partials/mbuf dead; reuse as fidx/fdist

    // ---- phase 2: same MFMA (deterministic), rmin-guarded pushes ----
    {
        float tc = tauv[q];
#pragma unroll 2
        for (int t = 0; t < 64; ++t) {
            uint4 au = {0u, 0u, 0u, 0u};
            if (rg == 0) {
                uint2 pd = Pm[cbase + t * 16 + qcol];
                au.x = pd.x; au.y = pd.y; au.z = pd.x; au.w = pd.y;
            }
            f4 d = __builtin_amdgcn_mfma_f32_16x16x32_f16(
                __builtin_bit_cast(h8, au), bq, (f4)0.0f, 0, 0, 0);
            float rmin = fminf(fminf(d[0], d[1]), fminf(d[2], d[3]));
            if (rmin <= tc) {
#pragma unroll
                for (int r = 0; r < 4; ++r) {
                    if (d[r] <= tc) {
                        int pos = atomicAdd(&qcnt[q], 1);
                        if (pos < FCAP) fidx[pos * 64 + q] = (unsigned)(cbase + t * 16 + rg * 4 + r);
                    }
                }
            }
        }
    }
    __syncthreads();

    // ---- sweep: exact f32 distances, fully parallel gathers ----
    for (int e = tid; e < FCAP * 64; e += 1024) {
        int j = e >> 6, qq = e & 63;
        int nc = qcnt[qq]; nc = nc > FCAP ? FCAP : nc;
        if (j < nc) {
            float4 Qf = pb[(blockIdx.x << 6) + qq];
            fdist[e] = dist2(Qf, pb[fidx[e]]);
        }
    }
    __syncthreads();

    // ---- final: lexicographic (d asc, idx asc) top-16; overflow fallback ----
    if (tid < 64) {
        int nqf = (blockIdx.x << 6) + tid;
        float4 Qf = pb[nqf];
        float bd[16]; int bi[16];
#pragma unroll
        for (int j = 0; j < 16; ++j) { bd[j] = __builtin_inff(); bi[j] = 0; }
        int cnt = qcnt[tid];
        if (cnt <= FCAP) {
            for (int j = 0; j < cnt; ++j) {
                float x  = fdist[j * 64 + tid];
                int   xi = (int)fidx[j * 64 + tid];
                if (x < bd[15] || (x == bd[15] && xi < bi[15])) {
#pragma unroll
                    for (int t = 0; t < 16; ++t) {
                        bool c = (x < bd[t]) || (x == bd[t] && xi < bi[t]);
                        float nd = c ? x  : bd[t];
                        int   ni = c ? xi : bi[t];
                        float od = c ? bd[t] : x;
                        int   oi = c ? bi[t] : xi;
                        bd[t] = nd; bi[t] = ni; x = od; xi = oi;
                    }
                }
            }
        } else {
            // safety fallback: exact brute-force scan (P ~ 1e-10, never expected)
            for (int m = 0; m < NPTS; ++m) {
                float x = dist2(Qf, pb[m]);
                int  xi = m;
                if (x < bd[15] || (x == bd[15] && xi < bi[15])) {
#pragma unroll
                    for (int t = 0; t < 16; ++t) {
                        bool c = (x < bd[t]) || (x == bd[t] && xi < bi[t]);
                        float nd = c ? x  : bd[t];
                        int   ni = c ? xi : bi[t];
                        float od = c ? bd[t] : x;
                        int   oi = c ? bi[t] : xi;
                        bd[t] = nd; bi[t] = ni; x = od; xi = oi;
                    }
                }
            }
        }
        int* op = idxout + ((size_t)b * NPTS + nqf) * KNN;
#pragma unroll
        for (int j = 0; j < 16; ++j) op[j] = bi[j];
    }
}

// ---------------------------------------------------------------------------
// Kernel B: fully-register MFMA MLP (unchanged from rounds 4-12).
// ---------------------------------------------------------------------------
__global__ __launch_bounds__(256, 2) void mlp_kernel(
    const float4* __restrict__ pts4, const int* __restrict__ idxin,
    const float* __restrict__ W0, const float* __restrict__ b0,
    const float* __restrict__ W1, const float* __restrict__ b1,
    const float* __restrict__ W2, const float* __restrict__ b2,
    float* __restrict__ out) {

    int tid  = threadIdx.x;
    int wave = tid >> 6, lane = tid & 63;
    int g = lane >> 4, i = lane & 15;

    h2 w0x[8], w0y[8], w0z[8], w0b[8];
#pragma unroll
    for (int s = 0; s < 2; ++s)
#pragma unroll
        for (int v = 0; v < 4; ++v) {
            int c0 = 32 * s + 8 * g + 2 * v;
            w0x[s * 4 + v] = pk2(W0[c0 * 3 + 0], W0[c0 * 3 + 3]);
            w0y[s * 4 + v] = pk2(W0[c0 * 3 + 1], W0[c0 * 3 + 4]);
            w0z[s * 4 + v] = pk2(W0[c0 * 3 + 2], W0[c0 * 3 + 5]);
            w0b[s * 4 + v] = pk2(b0[c0], b0[c0 + 1]);
        }
    h2 b1p[8];
#pragma unroll
    for (int s = 0; s < 2; ++s)
#pragma unroll
        for (int v = 0; v < 4; ++v) {
            int c0 = 32 * s + 16 * (v >> 1) + 4 * g + 2 * (v & 1);
            b1p[s * 4 + v] = pk2(b1[c0], b1[c0 + 1]);
        }
    h8 wf1[4][2];
#pragma unroll
    for (int t = 0; t < 4; ++t)
#pragma unroll
        for (int s = 0; s < 2; ++s) {
            const float* p = W1 + (16 * t + i) * 64 + 32 * s + 8 * g;
            h8 f;
#pragma unroll
            for (int j = 0; j < 8; ++j) f[j] = (_Float16)p[j];
            wf1[t][s] = f;
        }
    h8 wf2[8][2];
#pragma unroll
    for (int t = 0; t < 8; ++t)
#pragma unroll
        for (int s = 0; s < 2; ++s) {
            const float* p = W2 + (16 * t + i) * 64;
            h8 f;
#pragma unroll
            for (int j = 0; j < 8; ++j) {
                int vc = 32 * s + 16 * (j >> 2) + 4 * g + (j & 3);
                f[j] = (_Float16)p[vc];
            }
            wf2[t][s] = f;
        }

    int gw = blockIdx.x * 4 + wave;
    int b  = gw >> 8;
    int n0 = (gw & 255) * 16;

    const float4* pb = pts4 + (size_t)b * NPTS;
    float4 q = pb[n0 + i];
    const int* ip = idxin + ((size_t)b * NPTS + n0 + i) * KNN;

    float mx[8][4];
#pragma unroll
    for (int t = 0; t < 8; ++t)
#pragma unroll
        for (int r = 0; r < 4; ++r) mx[t][r] = -3.4e38f;

    for (int it = 0; it < KNN; ++it) {
        int mi = ip[it];
        float4 p = pb[mi];
        float rx = p.x - q.x, ry = p.y - q.y, rz = p.z - q.z;
        h2 rxx = pk2(rx, rx), ryy = pk2(ry, ry), rzz = pk2(rz, rz);

        h8 h0f[2];
#pragma unroll
        for (int s = 0; s < 2; ++s)
#pragma unroll
            for (int v = 0; v < 4; ++v) {
                h2 hh = __builtin_elementwise_fma(w0z[s * 4 + v], rzz,
                         __builtin_elementwise_fma(w0y[s * 4 + v], ryy,
                          __builtin_elementwise_fma(w0x[s * 4 + v], rxx, w0b[s * 4 + v])));
                hh = __builtin_elementwise_max(hh, (h2)(_Float16)0.0f);
                h0f[s][2 * v]     = hh.x;
                h0f[s][2 * v + 1] = hh.y;
            }

        f4 d1[4];
#pragma unroll
        for (int t = 0; t < 4; ++t) {
            d1[t] = (f4)0.0f;
#pragma unroll
            for (int s = 0; s < 2; ++s)
                d1[t] = __builtin_amdgcn_mfma_f32_16x16x32_f16(wf1[t][s], h0f[s], d1[t], 0, 0, 0);
        }

        h8 h1f[2];
#pragma unroll
        for (int s = 0; s < 2; ++s)
#pragma unroll
            for (int v = 0; v < 4; ++v) {
                int t = 2 * s + (v >> 1), r0 = 2 * (v & 1);
                h2 w = pk2(d1[t][r0], d1[t][r0 + 1]);
                w = w + b1p[s * 4 + v];
                w = __builtin_elementwise_max(w, (h2)(_Float16)0.0f);
                h1f[s][2 * v]     = w.x;
                h1f[s][2 * v + 1] = w.y;
            }

#pragma unroll
        for (int t = 0; t < 8; ++t) {
            f4 d2 = (f4)0.0f;
#pragma unroll
            for (int s = 0; s < 2; ++s)
                d2 = __builtin_amdgcn_mfma_f32_16x16x32_f16(wf2[t][s], h1f[s], d2, 0, 0, 0);
#pragma unroll
            for (int r = 0; r < 4; ++r) mx[t][r] = fmaxf(mx[t][r], d2[r]);
        }
    }

    size_t ob = (size_t)b * 128 * NPTS + n0 + i;
#pragma unroll
    for (int t = 0; t < 8; ++t)
#pragma unroll
        for (int r = 0; r < 4; ++r) {
            int chn = 16 * t + 4 * g + r;
            float v = fmaxf(mx[t][r] + b2[chn], 0.0f);
            out[ob + (size_t)chn * NPTS] = v;
        }
}

// ---------------------------------------------------------------------------
extern "C" void kernel_launch(void* const* d_in, const int* in_sizes, int n_in,
                              void* d_out, int out_size, void* d_ws, size_t ws_size,
                              hipStream_t stream) {
    (void)in_sizes; (void)n_in; (void)out_size; (void)ws_size;
    const float* xyz = (const float*)d_in[0];
    const float* W0  = (const float*)d_in[1];
    const float* b0  = (const float*)d_in[2];
    const float* W1  = (const float*)d_in[3];
    const float* b1  = (const float*)d_in[4];
    const float* W2  = (const float*)d_in[5];
    const float* b2  = (const float*)d_in[6];
    float* out = (float*)d_out;

    char* ws = (char*)d_ws;
    float4* pts4 = (float4*)ws;                                     // 512 KB
    int*    idxb = (int*)(ws + (size_t)NB * NPTS * sizeof(float4)); // 2 MB

    prep_kernel<<<dim3(NB * NPTS / 256), dim3(256), 0, stream>>>(xyz, pts4);
    knn_kernel<<<dim3(NPTS / 64, NB), dim3(1024), 0, stream>>>(pts4, idxb);
    mlp_kernel<<<dim3(512), dim3(256), 0, stream>>>(
        pts4, idxb, W0, b0, W1, b1, W2, b2, out);
}

// Round 14
// 106.926 us; speedup vs baseline: 1.5442x; 1.1060x over previous
//
#include <hip/hip_runtime.h>
#include <cstddef>

#define NB   8
#define NPTS 4096
#define KNN  16
#define FCAP 64    // per-query collected-candidate capacity

typedef _Float16 h2 __attribute__((ext_vector_type(2)));
typedef _Float16 h8 __attribute__((ext_vector_type(8)));
typedef float    f4 __attribute__((ext_vector_type(4)));
typedef float    f16f __attribute__((ext_vector_type(16)));

static __device__ __forceinline__ h2 pk2(float a, float b) {
    return __builtin_bit_cast(h2, __builtin_amdgcn_cvt_pkrtz(a, b));
}
static __device__ __forceinline__ unsigned bch(h2 v) {
    return __builtin_bit_cast(unsigned, v);
}

#if __has_builtin(__builtin_amdgcn_fmed3f)
static __device__ __forceinline__ float MED3(float a, float b, float c) {
    return __builtin_amdgcn_fmed3f(a, b, c);
}
#else
static __device__ __forceinline__ float MED3(float a, float b, float c) {
    return fmaxf(fminf(a, b), fminf(fmaxf(a, b), c));
}
#endif

// Exact f32 distance (sq-form). Same fmaf nesting as prep's sq -> self-dist
// is exactly 0. Used ONLY for the exact candidate distances.
static __device__ __forceinline__ float dist2(float4 Q, float4 p) {
    float dot = fmaf(Q.z, p.z, fmaf(Q.y, p.y, Q.x * p.x));
    return fmaf(-2.0f, dot, Q.w + p.w);
}

// ---------------------------------------------------------------------------
// Kernel P: pack pts4[b][n] = (x, y, z, x*x+y*y+z*z) from xyz[B][3][N]
// ---------------------------------------------------------------------------
__global__ __launch_bounds__(256) void prep_kernel(const float* __restrict__ xyz,
                                                   float4* __restrict__ pts4) {
    int i = blockIdx.x * 256 + threadIdx.x;
    int b = i >> 12;
    int n = i & (NPTS - 1);
    const float* base = xyz + (size_t)b * 3 * NPTS;
    float x = base[n];
    float y = base[NPTS + n];
    float z = base[2 * NPTS + n];
    float sq = fmaf(z, z, fmaf(y, y, x * x));   // same nesting as dist2's dot
    pts4[i] = make_float4(x, y, z, sq);
}

// ---------------------------------------------------------------------------
// Kernel A: exact 16-NN, 32x32x16 MFMA pruning keys (4x bigger tiles than
// round 13: 1024 keys/MFMA, per-tile overhead amortized 4x).
//  Key g = p_h.(u_h+u_l) + s_h (identical math to rounds 12/13):
//   A (cands): lanes hl=0 hold row=col: k0-3=(xh,yh,zh,sh), k4-7=dup;
//              lanes hl=1 (k8-15) zero.
//   B (query): lanes hl=0: k0-7=(uxh,uyh,uzh,1,uxl,uyl,uzl,0); hl=1 zero.
//   D: col=lane&31 (query), row=(r&3)+8*(r>>2)+4*hl  [verified 32x32 layout].
//  Phase 1: per lane min-of-16 D regs (15-op tree) -> sorted-4 chain.
//  tau_hat looser (16th of 256 tile-group minima ~ d17-d20); coverage proof
//  unchanged (subset order stats + E-chain); qcnt ~24 << FCAP.
//  Per-query tight E, parallel exact f32 sweep, lexicographic final select
//  == jax.lax.top_k tie-break: all identical to round 13.
// ---------------------------------------------------------------------------
__global__ __launch_bounds__(1024, 8) void knn_kernel(const float4* __restrict__ pts4,
                                                      int* __restrict__ idxout) {
    __shared__ uint2 Pm[NPTS];                        // 32 KB (xh,yh | zh,sh)
    __shared__ char  sbuf[32768];                     // 32 KB phase-shared
    __shared__ float tauv[64];
    __shared__ int   qcnt[64];
    __shared__ unsigned pmaxu, smaxu;

    float*    partials = (float*)sbuf;                // [64 slots][64 q] 16 KB
    float*    mbuf     = (float*)(sbuf + 16384);      // [4*16][64 q]    16 KB
    unsigned* fidx     = (unsigned*)sbuf;             // [FCAP][64 q]    16 KB
    float*    fdist    = (float*)(sbuf + 16384);      // [FCAP][64 q]    16 KB

    int tid = threadIdx.x;
    int b   = blockIdx.y;
    const float4* pb = pts4 + (size_t)b * NPTS;

    if (tid == 0) { pmaxu = 0u; smaxu = 0u; }
    __syncthreads();

    // ---- stage (xh,yh|zh,sh); reduce exact pmax/smax of the batch ----
    {
        float lm = 0.0f, ls = 0.0f;
        for (int j = tid; j < NPTS; j += 1024) {
            float4 p = pb[j];
            lm = fmaxf(lm, fmaxf(fabsf(p.x), fmaxf(fabsf(p.y), fabsf(p.z))));
            ls = fmaxf(ls, p.w);
            h2 lo = { (_Float16)p.x, (_Float16)p.y };
            h2 hi = { (_Float16)p.z, (_Float16)p.w };
            Pm[j].x = bch(lo);
            Pm[j].y = bch(hi);
        }
        atomicMax(&pmaxu, __builtin_bit_cast(unsigned, lm));   // f32>=0: uint order
        atomicMax(&smaxu, __builtin_bit_cast(unsigned, ls));
    }

    int wave = tid >> 6, lane = tid & 63;
    int g  = wave >> 3;           // query half 0..1 (32 q each)
    int c  = wave & 7;            // candidate chunk 0..7 (512 cands)
    int col = lane & 31;          // A-row / B-col / D-col
    int hl  = lane >> 5;          // lane half (k-slot group / D row group)
    int q  = g * 32 + col;        // 0..63
    int nq = (blockIdx.x << 6) + q;
    int cbase = c * 512;

    float4 qf = pb[nq];
    float uxf = -2.0f * qf.x, uyf = -2.0f * qf.y, uzf = -2.0f * qf.z;  // exact
    _Float16 uxh = (_Float16)uxf, uyh = (_Float16)uyf, uzh = (_Float16)uzf;
    _Float16 uxl = (_Float16)(uxf - (float)uxh);
    _Float16 uyl = (_Float16)(uyf - (float)uyh);
    _Float16 uzl = (_Float16)(uzf - (float)uzh);
    uint4 bu = {0u, 0u, 0u, 0u};
    if (hl == 0) {
        h2 b01 = {uxh, uyh}, b23 = {uzh, (_Float16)1.0f};
        h2 b45 = {uxl, uyl}, b67 = {uzl, (_Float16)0.0f};
        bu.x = bch(b01); bu.y = bch(b23); bu.z = bch(b45); bu.w = bch(b67);
    }
    h8 bq = __builtin_bit_cast(h8, bu);
    __syncthreads();

    // ---- phase 1: 16 MFMA tiles (32 cands x 32 q), min16 + sorted-4 ----
    {
        float c0 = __builtin_inff(), c1 = c0, c2 = c0, c3 = c0;
#pragma unroll 2
        for (int t = 0; t < 16; ++t) {
            uint4 au = {0u, 0u, 0u, 0u};
            if (hl == 0) {
                uint2 pd = Pm[cbase + t * 32 + col];
                au.x = pd.x; au.y = pd.y; au.z = pd.x; au.w = pd.y;  // k0-3 & k4-7
            }
            f16f d = __builtin_amdgcn_mfma_f32_32x32x16_f16(
                __builtin_bit_cast(h8, au), bq, (f16f)0.0f, 0, 0, 0);
            float a0 = fminf(d[0], d[1]),   a1 = fminf(d[2], d[3]);
            float a2 = fminf(d[4], d[5]),   a3 = fminf(d[6], d[7]);
            float a4 = fminf(d[8], d[9]),   a5 = fminf(d[10], d[11]);
            float a6 = fminf(d[12], d[13]), a7 = fminf(d[14], d[15]);
            float b0 = fminf(a0, a1), b1 = fminf(a2, a3);
            float b2 = fminf(a4, a5), b3 = fminf(a6, a7);
            float rmin = fminf(fminf(b0, b1), fminf(b2, b3));
            float p0 = c0, p1 = c1, p2 = c2;
            c0 = fminf(p0, rmin);
            c1 = MED3(rmin, p0, c1);
            c2 = MED3(rmin, p1, c2);
            c3 = MED3(rmin, p2, c3);
        }
        int sb = (c * 2 + hl) * 4;
        partials[(sb + 0) * 64 + q] = c0;
        partials[(sb + 1) * 64 + q] = c1;
        partials[(sb + 2) * 64 + q] = c2;
        partials[(sb + 3) * 64 + q] = c3;
    }
    __syncthreads();

    // ---- merge level 1: 4 mergers/query x 16 slots -> sorted-16 ----
    if (tid < 256) {
        int qq = tid & 63, k = tid >> 6;
        float mb[16];
#pragma unroll
        for (int j = 0; j < 16; ++j) mb[j] = __builtin_inff();
        for (int s = 0; s < 16; ++s) {
            float v = partials[(k * 16 + s) * 64 + qq];
            float prev = mb[0];
            mb[0] = fminf(mb[0], v);
#pragma unroll
            for (int i = 1; i < 16; ++i) {
                float cur = mb[i];
                mb[i] = MED3(v, prev, cur);
                prev = cur;
            }
        }
#pragma unroll
        for (int j = 0; j < 16; ++j) mbuf[(k * 16 + j) * 64 + qq] = mb[j];
    }
    __syncthreads();

    // ---- merge level 2: 16th of 4 sorted lists; per-query tight bound ----
    if (tid < 64) {
        float mb[16];
#pragma unroll
        for (int j = 0; j < 16; ++j) mb[j] = __builtin_inff();
        for (int k = 0; k < 4; ++k) {
            for (int j = 0; j < 16; ++j) {
                float v = mbuf[(k * 16 + j) * 64 + tid];
                if (v >= mb[15]) break;             // ascending list
                float prev = mb[0];
                mb[0] = fminf(mb[0], v);
#pragma unroll
                for (int i = 1; i < 16; ++i) {
                    float cur = mb[i];
                    mb[i] = MED3(v, prev, cur);
                    prev = cur;
                }
            }
        }
        float4 q2 = pb[(blockIdx.x << 6) + tid];
        float sumq = fabsf(q2.x) + fabsf(q2.y) + fabsf(q2.z);
        float qn   = sqrtf(q2.w);                   // |q| (q2.w = |q|^2 >= 0)
        float pmax = __builtin_bit_cast(float, pmaxu);
        float smax = __builtin_bit_cast(float, smaxu);
        const float r11c = 4.8828125e-4f;           // 2^-11
        float tau = mb[15];
        float E0  = smax * r11c + 2.0f * sumq * pmax * r11c + 1.0e-3f;
        float rad2 = fmaxf(tau + 2.0f * E0 + q2.w, 0.0f);
        float R   = qn + sqrtf(rad2);
        float Eq  = (R * R + 2.0f * sumq * R) * r11c + 6.0e-4f;
        Eq = fminf(Eq, E0);
        tauv[tid] = tau + 2.0f * Eq;
        qcnt[tid] = 0;
    }
    __syncthreads();   // partials/mbuf dead; reuse as fidx/fdist

    // ---- phase 2: same MFMA (deterministic), per-register compare/push ----
    {
        float tc = tauv[q];
#pragma unroll 1
        for (int t = 0; t < 16; ++t) {
            uint4 au = {0u, 0u, 0u, 0u};
            if (hl == 0) {
                uint2 pd = Pm[cbase + t * 32 + col];
                au.x = pd.x; au.y = pd.y; au.z = pd.x; au.w = pd.y;
            }
            f16f d = __builtin_amdgcn_mfma_f32_32x32x16_f16(
                __builtin_bit_cast(h8, au), bq, (f16f)0.0f, 0, 0, 0);
#pragma unroll
            for (int r = 0; r < 16; ++r) {
                if (d[r] <= tc) {
                    int pos = atomicAdd(&qcnt[q], 1);
                    if (pos < FCAP)
                        fidx[pos * 64 + q] =
                            (unsigned)(cbase + t * 32 + (r & 3) + 8 * (r >> 2) + 4 * hl);
                }
            }
        }
    }
    __syncthreads();

    // ---- sweep: exact f32 distances, fully parallel gathers ----
    for (int e = tid; e < FCAP * 64; e += 1024) {
        int j = e >> 6, qq = e & 63;
        int nc = qcnt[qq]; nc = nc > FCAP ? FCAP : nc;
        if (j < nc) {
            float4 Qf = pb[(blockIdx.x << 6) + qq];
            fdist[e] = dist2(Qf, pb[fidx[e]]);
        }
    }
    __syncthreads();

    // ---- final: lexicographic (d asc, idx asc) top-16; overflow fallback ----
    if (tid < 64) {
        int nqf = (blockIdx.x << 6) + tid;
        float4 Qf = pb[nqf];
        float bd[16]; int bi[16];
#pragma unroll
        for (int j = 0; j < 16; ++j) { bd[j] = __builtin_inff(); bi[j] = 0; }
        int cnt = qcnt[tid];
        if (cnt <= FCAP) {
            for (int j = 0; j < cnt; ++j) {
                float x  = fdist[j * 64 + tid];
                int   xi = (int)fidx[j * 64 + tid];
                if (x < bd[15] || (x == bd[15] && xi < bi[15])) {
#pragma unroll
                    for (int t = 0; t < 16; ++t) {
                        bool cc = (x < bd[t]) || (x == bd[t] && xi < bi[t]);
                        float nd = cc ? x  : bd[t];
                        int   ni = cc ? xi : bi[t];
                        float od = cc ? bd[t] : x;
                        int   oi = cc ? bi[t] : xi;
                        bd[t] = nd; bi[t] = ni; x = od; xi = oi;
                    }
                }
            }
        } else {
            // safety fallback: exact brute-force scan (P ~ 1e-10, never expected)
            for (int m = 0; m < NPTS; ++m) {
                float x = dist2(Qf, pb[m]);
                int  xi = m;
                if (x < bd[15] || (x == bd[15] && xi < bi[15])) {
#pragma unroll
                    for (int t = 0; t < 16; ++t) {
                        bool cc = (x < bd[t]) || (x == bd[t] && xi < bi[t]);
                        float nd = cc ? x  : bd[t];
                        int   ni = cc ? xi : bi[t];
                        float od = cc ? bd[t] : x;
                        int   oi = cc ? bi[t] : xi;
                        bd[t] = nd; bi[t] = ni; x = od; xi = oi;
                    }
                }
            }
        }
        int* op = idxout + ((size_t)b * NPTS + nqf) * KNN;
#pragma unroll
        for (int j = 0; j < 16; ++j) op[j] = bi[j];
    }
}

// ---------------------------------------------------------------------------
// Kernel B: fully-register MFMA MLP (unchanged from rounds 4-13).
// ---------------------------------------------------------------------------
__global__ __launch_bounds__(256, 2) void mlp_kernel(
    const float4* __restrict__ pts4, const int* __restrict__ idxin,
    const float* __restrict__ W0, const float* __restrict__ b0,
    const float* __restrict__ W1, const float* __restrict__ b1,
    const float* __restrict__ W2, const float* __restrict__ b2,
    float* __restrict__ out) {

    int tid  = threadIdx.x;
    int wave = tid >> 6, lane = tid & 63;
    int g = lane >> 4, i = lane & 15;

    h2 w0x[8], w0y[8], w0z[8], w0b[8];
#pragma unroll
    for (int s = 0; s < 2; ++s)
#pragma unroll
        for (int v = 0; v < 4; ++v) {
            int c0 = 32 * s + 8 * g + 2 * v;
            w0x[s * 4 + v] = pk2(W0[c0 * 3 + 0], W0[c0 * 3 + 3]);
            w0y[s * 4 + v] = pk2(W0[c0 * 3 + 1], W0[c0 * 3 + 4]);
            w0z[s * 4 + v] = pk2(W0[c0 * 3 + 2], W0[c0 * 3 + 5]);
            w0b[s * 4 + v] = pk2(b0[c0], b0[c0 + 1]);
        }
    h2 b1p[8];
#pragma unroll
    for (int s = 0; s < 2; ++s)
#pragma unroll
        for (int v = 0; v < 4; ++v) {
            int c0 = 32 * s + 16 * (v >> 1) + 4 * g + 2 * (v & 1);
            b1p[s * 4 + v] = pk2(b1[c0], b1[c0 + 1]);
        }
    h8 wf1[4][2];
#pragma unroll
    for (int t = 0; t < 4; ++t)
#pragma unroll
        for (int s = 0; s < 2; ++s) {
            const float* p = W1 + (16 * t + i) * 64 + 32 * s + 8 * g;
            h8 f;
#pragma unroll
            for (int j = 0; j < 8; ++j) f[j] = (_Float16)p[j];
            wf1[t][s] = f;
        }
    h8 wf2[8][2];
#pragma unroll
    for (int t = 0; t < 8; ++t)
#pragma unroll
        for (int s = 0; s < 2; ++s) {
            const float* p = W2 + (16 * t + i) * 64;
            h8 f;
#pragma unroll
            for (int j = 0; j < 8; ++j) {
                int vc = 32 * s + 16 * (j >> 2) + 4 * g + (j & 3);
                f[j] = (_Float16)p[vc];
            }
            wf2[t][s] = f;
        }

    int gw = blockIdx.x * 4 + wave;
    int b  = gw >> 8;
    int n0 = (gw & 255) * 16;

    const float4* pb = pts4 + (size_t)b * NPTS;
    float4 q = pb[n0 + i];
    const int* ip = idxin + ((size_t)b * NPTS + n0 + i) * KNN;

    float mx[8][4];
#pragma unroll
    for (int t = 0; t < 8; ++t)
#pragma unroll
        for (int r = 0; r < 4; ++r) mx[t][r] = -3.4e38f;

    for (int it = 0; it < KNN; ++it) {
        int mi = ip[it];
        float4 p = pb[mi];
        float rx = p.x - q.x, ry = p.y - q.y, rz = p.z - q.z;
        h2 rxx = pk2(rx, rx), ryy = pk2(ry, ry), rzz = pk2(rz, rz);

        h8 h0f[2];
#pragma unroll
        for (int s = 0; s < 2; ++s)
#pragma unroll
            for (int v = 0; v < 4; ++v) {
                h2 hh = __builtin_elementwise_fma(w0z[s * 4 + v], rzz,
                         __builtin_elementwise_fma(w0y[s * 4 + v], ryy,
                          __builtin_elementwise_fma(w0x[s * 4 + v], rxx, w0b[s * 4 + v])));
                hh = __builtin_elementwise_max(hh, (h2)(_Float16)0.0f);
                h0f[s][2 * v]     = hh.x;
                h0f[s][2 * v + 1] = hh.y;
            }

        f4 d1[4];
#pragma unroll
        for (int t = 0; t < 4; ++t) {
            d1[t] = (f4)0.0f;
#pragma unroll
            for (int s = 0; s < 2; ++s)
                d1[t] = __builtin_amdgcn_mfma_f32_16x16x32_f16(wf1[t][s], h0f[s], d1[t], 0, 0, 0);
        }

        h8 h1f[2];
#pragma unroll
        for (int s = 0; s < 2; ++s)
#pragma unroll
            for (int v = 0; v < 4; ++v) {
                int t = 2 * s + (v >> 1), r0 = 2 * (v & 1);
                h2 w = pk2(d1[t][r0], d1[t][r0 + 1]);
                w = w + b1p[s * 4 + v];
                w = __builtin_elementwise_max(w, (h2)(_Float16)0.0f);
                h1f[s][2 * v]     = w.x;
                h1f[s][2 * v + 1] = w.y;
            }

#pragma unroll
        for (int t = 0; t < 8; ++t) {
            f4 d2 = (f4)0.0f;
#pragma unroll
            for (int s = 0; s < 2; ++s)
                d2 = __builtin_amdgcn_mfma_f32_16x16x32_f16(wf2[t][s], h1f[s], d2, 0, 0, 0);
#pragma unroll
            for (int r = 0; r < 4; ++r) mx[t][r] = fmaxf(mx[t][r], d2[r]);
        }
    }

    size_t ob = (size_t)b * 128 * NPTS + n0 + i;
#pragma unroll
    for (int t = 0; t < 8; ++t)
#pragma unroll
        for (int r = 0; r < 4; ++r) {
            int chn = 16 * t + 4 * g + r;
            float v = fmaxf(mx[t][r] + b2[chn], 0.0f);
            out[ob + (size_t)chn * NPTS] = v;
        }
}

// ---------------------------------------------------------------------------
extern "C" void kernel_launch(void* const* d_in, const int* in_sizes, int n_in,
                              void* d_out, int out_size, void* d_ws, size_t ws_size,
                              hipStream_t stream) {
    (void)in_sizes; (void)n_in; (void)out_size; (void)ws_size;
    const float* xyz = (const float*)d_in[0];
    const float* W0  = (const float*)d_in[1];
    const float* b0  = (const float*)d_in[2];
    const float* W1  = (const float*)d_in[3];
    const float* b1  = (const float*)d_in[4];
    const float* W2  = (const float*)d_in[5];
    const float* b2  = (const float*)d_in[6];
    float* out = (float*)d_out;

    char* ws = (char*)d_ws;
    float4* pts4 = (float4*)ws;                                     // 512 KB
    int*    idxb = (int*)(ws + (size_t)NB * NPTS * sizeof(float4)); // 2 MB

    prep_kernel<<<dim3(NB * NPTS / 256), dim3(256), 0, stream>>>(xyz, pts4);
    knn_kernel<<<dim3(NPTS / 64, NB), dim3(1024), 0, stream>>>(pts4, idxb);
    mlp_kernel<<<dim3(512), dim3(256), 0, stream>>>(
        pts4, idxb, W0, b0, W1, b1, W2, b2, out);
}